// Round 1
// baseline (1689.627 us; speedup 1.0000x reference)
//
#include <hip/hip_runtime.h>
#include <hip/hip_bf16.h>

// Problem constants (static per reference)
#define NUM_E   8
#define D_IN    4096
#define D_OUT   4096
#define TPE     2048
#define T_TOTAL (NUM_E * TPE)

// Tile config: 128x128 tile, BK=32, 256 threads (4 waves, 2x2), each wave 64x64
#define BM 128
#define BN 128
#define BK 32

typedef __bf16 bf16_8 __attribute__((ext_vector_type(8)));
typedef __bf16 bf16_4 __attribute__((ext_vector_type(4)));
typedef float  f32x4  __attribute__((ext_vector_type(4)));

// out[m,n] = sum_k inp[m,k] * wgt[e][n,k]   (both K-contiguous: gemm_bt shape)
__global__ __launch_bounds__(256, 2)
void grouped_gemm_bf16_kernel(const float* __restrict__ inp,
                              const float* __restrict__ wgt,
                              float* __restrict__ out)
{
    const int nTile = blockIdx.x;          // 0..31
    const int mTile = blockIdx.y;          // 0..127 (global row tiles)
    const int expert = mTile >> 4;         // 2048/128 = 16 m-tiles per expert
    const int rowStart = mTile * BM;
    const int colStart = nTile * BN;

    const float* Abase = inp + (size_t)rowStart * D_IN;
    const float* Bbase = wgt + (size_t)expert * D_OUT * D_IN + (size_t)colStart * D_IN;

    // LDS layout: [k>>3][row][k&7] -> each MFMA fragment is 16B contiguous,
    // 16B aligned (ds_read_b128), 2-way bank aliasing only (free per m136).
    __shared__ __bf16 As[4][BM][8];
    __shared__ __bf16 Bs[4][BN][8];

    const int tid  = threadIdx.x;
    const int lane = tid & 63;
    const int wave = tid >> 6;             // 0..3
    const int wm   = (wave >> 1) * 64;     // wave's 64x64 sub-tile origin
    const int wn   = (wave & 1) * 64;

    const int kq = lane >> 4;              // k-quarter (which 8-wide k block)
    const int lr = lane & 15;              // row-within-16 for A/B fragments

    f32x4 acc[4][4];
    #pragma unroll
    for (int i = 0; i < 4; ++i)
        #pragma unroll
        for (int j = 0; j < 4; ++j)
            acc[i][j] = (f32x4){0.f, 0.f, 0.f, 0.f};

    for (int k0 = 0; k0 < D_IN; k0 += BK) {
        __syncthreads();   // previous compute must finish reading LDS

        // Stage: 128x32 fp32 -> bf16 per matrix. 256 thr x 4 iters x float4.
        // Consecutive lanes get consecutive k -> 128B coalesced global loads.
        #pragma unroll
        for (int it = 0; it < 4; ++it) {
            const int idx = (it * 256 + tid) * 4;     // element in 128x32 tile
            const int row = idx >> 5;                 // /32
            const int col = idx & 31;                 // %32, multiple of 4
            const float4 av = *reinterpret_cast<const float4*>(
                Abase + (size_t)row * D_IN + k0 + col);
            const float4 bv = *reinterpret_cast<const float4*>(
                Bbase + (size_t)row * D_IN + k0 + col);
            bf16_4 a4, b4;
            a4.x = (__bf16)av.x; a4.y = (__bf16)av.y;
            a4.z = (__bf16)av.z; a4.w = (__bf16)av.w;
            b4.x = (__bf16)bv.x; b4.y = (__bf16)bv.y;
            b4.z = (__bf16)bv.z; b4.w = (__bf16)bv.w;
            *reinterpret_cast<bf16_4*>(&As[col >> 3][row][col & 7]) = a4;
            *reinterpret_cast<bf16_4*>(&Bs[col >> 3][row][col & 7]) = b4;
        }
        __syncthreads();

        // Fragments: A[m=lane&15][k=kq*8+j], B[k=kq*8+j][n=lane&15] (=W[n][k])
        bf16_8 afrag[4], bfrag[4];
        #pragma unroll
        for (int mt = 0; mt < 4; ++mt)
            afrag[mt] = *reinterpret_cast<const bf16_8*>(&As[kq][wm + mt * 16 + lr][0]);
        #pragma unroll
        for (int nt = 0; nt < 4; ++nt)
            bfrag[nt] = *reinterpret_cast<const bf16_8*>(&Bs[kq][wn + nt * 16 + lr][0]);

        #pragma unroll
        for (int mt = 0; mt < 4; ++mt)
            #pragma unroll
            for (int nt = 0; nt < 4; ++nt)
                acc[mt][nt] = __builtin_amdgcn_mfma_f32_16x16x32_bf16(
                    afrag[mt], bfrag[nt], acc[mt][nt], 0, 0, 0);
    }

    // Epilogue: C/D layout col=lane&15, row=(lane>>4)*4+r (m89/m91-verified)
    const int cn = lane & 15;
    const int cr = (lane >> 4) * 4;
    #pragma unroll
    for (int mt = 0; mt < 4; ++mt) {
        #pragma unroll
        for (int nt = 0; nt < 4; ++nt) {
            #pragma unroll
            for (int r = 0; r < 4; ++r) {
                const int m = wm + mt * 16 + cr + r;
                const int n = wn + nt * 16 + cn;
                out[(size_t)(rowStart + m) * D_OUT + colStart + n] = acc[mt][nt][r];
            }
        }
    }
}

extern "C" void kernel_launch(void* const* d_in, const int* in_sizes, int n_in,
                              void* d_out, int out_size, void* d_ws, size_t ws_size,
                              hipStream_t stream) {
    const float* inp = (const float*)d_in[0];   // [T_TOTAL, D_IN] fp32
    const float* wgt = (const float*)d_in[1];   // [E, D_OUT, D_IN] fp32
    // d_in[2] = num_tokens_per_expert: static 2048 each (reference reshapes
    // assuming equal counts), hardcoded in the kernel's expert indexing.
    float* out = (float*)d_out;                 // [T_TOTAL, D_OUT] fp32

    dim3 grid(D_OUT / BN, T_TOTAL / BM);        // 32 x 128 = 4096 blocks
    grouped_gemm_bf16_kernel<<<grid, 256, 0, stream>>>(inp, wgt, out);
}